// Round 9
// baseline (2507.006 us; speedup 1.0000x reference)
//
#include <hip/hip_runtime.h>
#include <math.h>

#define NPTS 16384
#define NBATCH 8
#define CIN 128
#define COUT 256
#define NP 1024
#define NS 32

#define NCELL 512     // 8x8x8 Morton cells
#define FPS_T 1024    // 16 waves
#define NTILE 16      // tiles per wave
#define TSZ 64        // points per tile (one per lane)

// ---------------- spatial sort preprocessing ----------------
__device__ __forceinline__ int cell_of(float x, float y, float z)
{
  int ix = (int)(x * 8.0f); ix = ix < 0 ? 0 : (ix > 7 ? 7 : ix);
  int iy = (int)(y * 8.0f); iy = iy < 0 ? 0 : (iy > 7 ? 7 : iy);
  int iz = (int)(z * 8.0f); iz = iz < 0 ? 0 : (iz > 7 ? 7 : iz);
  int m = 0;
#pragma unroll
  for (int b = 0; b < 3; ++b)
    m |= (((ix >> b) & 1) << (3 * b)) | (((iy >> b) & 1) << (3 * b + 1))
       | (((iz >> b) & 1) << (3 * b + 2));
  return m;
}

__global__ void zero_hist_kernel(int* __restrict__ hist)
{
  hist[blockIdx.x * NCELL + threadIdx.x] = 0;
}

__global__ void hist_kernel(const float* __restrict__ xyz, int* __restrict__ hist)
{
  const int i = blockIdx.x * 256 + threadIdx.x;
  const int b = i >> 14, n = i & (NPTS - 1);
  const float* p = xyz + ((size_t)b * NPTS + n) * 3;
  atomicAdd(&hist[b * NCELL + cell_of(p[0], p[1], p[2])], 1);
}

__global__ void scan_kernel(const int* __restrict__ hist, int* __restrict__ cursor)
{
  __shared__ int s[NCELL];
  const int b = blockIdx.x, t = threadIdx.x;
  const int h = hist[b * NCELL + t];
  s[t] = h;
  __syncthreads();
  for (int off = 1; off < NCELL; off <<= 1) {
    const int v = (t >= off) ? s[t - off] : 0;
    __syncthreads();
    s[t] += v;
    __syncthreads();
  }
  cursor[b * NCELL + t] = s[t] - h;   // exclusive
}

// Plain sorted-order outputs (sorted pos p = Morton rank within batch).
__global__ void scatter_kernel(const float* __restrict__ xyz, int* __restrict__ cursor,
                               float2* __restrict__ sxy2S, float* __restrict__ szS,
                               int* __restrict__ siS)
{
  const int i = blockIdx.x * 256 + threadIdx.x;
  const int b = i >> 14, n = i & (NPTS - 1);
  const float* p = xyz + ((size_t)b * NPTS + n) * 3;
  const float x = p[0], y = p[1], z = p[2];
  const int pos = atomicAdd(&cursor[b * NCELL + cell_of(x, y, z)], 1);
  const size_t o = (size_t)b * NPTS + pos;
  sxy2S[o] = make_float2(x, y);
  szS[o] = z;
  siS[o] = n;
}

// ---------------- DPP helpers ----------------
template <int CTRL>
__device__ __forceinline__ void dpp_max64(unsigned& hi, unsigned& lo)
{
  const unsigned ohi = (unsigned)__builtin_amdgcn_update_dpp((int)hi, (int)hi, CTRL, 0xF, 0xF, false);
  const unsigned olo = (unsigned)__builtin_amdgcn_update_dpp((int)lo, (int)lo, CTRL, 0xF, 0xF, false);
  const bool t = (ohi > hi) || (ohi == hi && olo > lo);
  hi = t ? ohi : hi;
  lo = t ? olo : lo;
}
template <int CTRL>
__device__ __forceinline__ float dppmaxf(float v)
{
  const float o = __uint_as_float((unsigned)__builtin_amdgcn_update_dpp(
      (int)__float_as_uint(v), (int)__float_as_uint(v), CTRL, 0xF, 0xF, false));
  return fmaxf(v, o);
}
template <int CTRL>
__device__ __forceinline__ float dppminf(float v)
{
  const float o = __uint_as_float((unsigned)__builtin_amdgcn_update_dpp(
      (int)__float_as_uint(v), (int)__float_as_uint(v), CTRL, 0xF, 0xF, false));
  return fminf(v, o);
}
template <int CTRL>
__device__ __forceinline__ unsigned dppmaxu(unsigned v)
{
  const unsigned o = (unsigned)__builtin_amdgcn_update_dpp((int)v, (int)v, CTRL, 0xF, 0xF, false);
  return v > o ? v : o;
}
#define RED6F(v) v = dppmaxf<0x111>(v); v = dppmaxf<0x112>(v); v = dppmaxf<0x114>(v); \
                 v = dppmaxf<0x118>(v); v = dppmaxf<0x142>(v); v = dppmaxf<0x143>(v);
#define RED6FN(v) v = dppminf<0x111>(v); v = dppminf<0x112>(v); v = dppminf<0x114>(v); \
                  v = dppminf<0x118>(v); v = dppminf<0x142>(v); v = dppminf<0x143>(v);
#define RED6U(v) v = dppmaxu<0x111>(v); v = dppmaxu<0x112>(v); v = dppmaxu<0x114>(v); \
                 v = dppmaxu<0x118>(v); v = dppmaxu<0x142>(v); v = dppmaxu<0x143>(v);

// ---------------- FPS ----------------
// 1 block/batch, 1024 thr (16 waves). Lane l, slot j owns sorted point
// w*1024 + j*64 + l -> tile j = 64 CONSECUTIVE Morton points (bbox side ~0.16
// vs the wave's 0.4). Lane j<16 carries tile j's bbox + cached exact key
// (maxdist, invpid<<14|spos). Per iter: lane-parallel tile tests -> ballot ->
// readfirstlane -> 16 compile-time s_cbranch tile blocks (issue cost only for
// ACTIVE 64-pt tiles; round-8 culled at 1024-pt wave granularity = ~40%
// active; 64-pt tiles ~5-10%). Tie-break exact: lazy phase-B u32-DPP over
// bit-matching lanes. XY in LDS at sorted pos (winner xy direct); z from szS.
__global__ __launch_bounds__(FPS_T)
void fps_kernel(const float* __restrict__ xyz,
                const float2* __restrict__ sxy2S, const float* __restrict__ szS,
                const int* __restrict__ siS, int* __restrict__ fps_idx)
{
#pragma clang fp contract(off)
  __shared__ float2 XY[NPTS];                   // 128 KB, sorted order
  __shared__ unsigned long long redk[2][16];
  __shared__ float tb[16][NTILE][6];            // init-time tile bboxes
  __shared__ unsigned tk[16][NTILE];            // init-time tile sel
  const int b = blockIdx.x;
  const int t = threadIdx.x;
  const int lane = t & 63, w = t >> 6;
  const int j16 = lane & 15;
  const int wbase = w * (NTILE * TSZ);
  const float* __restrict__ X = xyz + (size_t)b * NPTS * 3;
  const float* __restrict__ ZS = szS + (size_t)b * NPTS;
  const size_t B0 = (size_t)b * NPTS;

  float z[NTILE], dist[NTILE];
  unsigned pl[NTILE];
#pragma unroll
  for (int j = 0; j < NTILE; ++j) {
    const int sp = wbase + j * TSZ + lane;
    const float2 v = sxy2S[B0 + sp];            // coalesced
    XY[sp] = v;                                 // ds_write_b64, conflict-free
    z[j] = ZS[sp];
    const int pid = siS[B0 + sp];
    pl[j] = ((unsigned)(pid ^ 0x3FFF) << 14) | (unsigned)sp;
    dist[j] = 1e10f;
    // tile bbox + init sel (one-time)
    float xn = v.x, xx = v.x, yn = v.y, yx = v.y, zn = z[j], zx = z[j];
    RED6FN(xn) RED6F(xx) RED6FN(yn) RED6F(yx) RED6FN(zn) RED6F(zx)
    unsigned sl = pl[j];
    RED6U(sl)
    if (lane == 63) {
      tb[w][j][0] = xn; tb[w][j][1] = xx; tb[w][j][2] = yn;
      tb[w][j][3] = yx; tb[w][j][4] = zn; tb[w][j][5] = zx;
      tk[w][j] = sl;
    }
  }
  __syncthreads();
  const float bxn = tb[w][j16][0], bxx = tb[w][j16][1];
  const float byn = tb[w][j16][2], byx = tb[w][j16][3];
  const float bzn = tb[w][j16][4], bzx = tb[w][j16][5];
  unsigned kh_t = __float_as_uint(1e10f);       // cached tile key (lane j16 = tile j16)
  unsigned kl_t = tk[w][j16];
  __syncthreads();

  unsigned wkh_c = __float_as_uint(1e10f), wkl_c = 0;  // cached wave key
  int cur = 0;
  float lx = X[0], ly = X[1], lz = X[2];

  for (int k = 0; k < NP; ++k) {
    if (t == 0) fps_idx[b * NP + k] = cur;

    // lane-parallel exact tile test (lane tests tile j16; bits 0..15 used)
    const float ddx = fmaxf(fmaxf(bxn - lx, lx - bxx), 0.0f);
    const float ddy = fmaxf(fmaxf(byn - ly, ly - byx), 0.0f);
    const float ddz = fmaxf(fmaxf(bzn - lz, lz - bzx), 0.0f);
    const float db2 = ((ddx * ddx) + (ddy * ddy)) + (ddz * ddz);
    const bool act = db2 <= __uint_as_float(kh_t) * 1.00001f;
    const unsigned msk = __builtin_amdgcn_readfirstlane(
        (unsigned)__ballot(act) & 0xFFFFu);     // SGPR -> s_cbranch guards

    if (msk) {
#define DO_TILE(J)                                                             \
      if (msk & (1u << (J))) {                                                 \
        const float2 v = XY[wbase + (J) * TSZ + lane];                         \
        const float dx = v.x - lx, dy = v.y - ly, dz = z[(J)] - lz;            \
        const float d = ((dx * dx) + (dy * dy)) + (dz * dz);                   \
        const float nd = fminf(dist[(J)], d);                                  \
        dist[(J)] = nd;                                                        \
        float mm = nd;                                                         \
        RED6F(mm)                                                              \
        const unsigned mh = (unsigned)__builtin_amdgcn_readlane(               \
            __float_as_int(mm), 63);                                           \
        unsigned cd = (__float_as_uint(nd) == mh) ? pl[(J)] : 0u;              \
        RED6U(cd)                                                              \
        const unsigned sl = (unsigned)__builtin_amdgcn_readlane((int)cd, 63);  \
        if (j16 == (J)) { kh_t = mh; kl_t = sl; }                              \
      }
      DO_TILE(0)  DO_TILE(1)  DO_TILE(2)  DO_TILE(3)
      DO_TILE(4)  DO_TILE(5)  DO_TILE(6)  DO_TILE(7)
      DO_TILE(8)  DO_TILE(9)  DO_TILE(10) DO_TILE(11)
      DO_TILE(12) DO_TILE(13) DO_TILE(14) DO_TILE(15)
#undef DO_TILE
      // recompute wave key (lanes 16-63 duplicate tiles 0-15 -> full reduce ok)
      unsigned h = kh_t, l2 = kl_t;
      dpp_max64<0x111>(h, l2);
      dpp_max64<0x112>(h, l2);
      dpp_max64<0x114>(h, l2);
      dpp_max64<0x118>(h, l2);
      dpp_max64<0x142>(h, l2);
      dpp_max64<0x143>(h, l2);
      wkh_c = (unsigned)__builtin_amdgcn_readlane((int)h, 63);
      wkl_c = (unsigned)__builtin_amdgcn_readlane((int)l2, 63);
    }
    const int p = k & 1;
    if (lane == 0)
      redk[p][w] = ((unsigned long long)wkh_c << 32) | wkl_c;
    __syncthreads();

    // cross-wave combine; speculative winner loads before the DPP combine
    const unsigned long long kj = redk[p][lane & 15];
    const unsigned shi = (unsigned)(kj >> 32), slo = (unsigned)kj;
    const int sposj = (int)(slo & 0x3FFFu);
    const float sgz = ZS[sposj];                // global (L2), overlapped
    const float2 sxy = XY[sposj];               // LDS direct (sorted layout)
    unsigned h2 = shi, l3 = slo;
    dpp_max64<0x111>(h2, l3);
    dpp_max64<0x112>(h2, l3);
    dpp_max64<0x114>(h2, l3);
    dpp_max64<0x118>(h2, l3);                   // lane 15 of each row = global max
    const unsigned kmh = (unsigned)__builtin_amdgcn_readlane((int)h2, 15);
    const unsigned kml = (unsigned)__builtin_amdgcn_readlane((int)l3, 15);
    cur = (int)((kml >> 14) & 0x3FFFu) ^ 0x3FFF;
    const unsigned long long tmsk = __ballot(shi == kmh && slo == kml) & 0xFFFFull;
    const int bwl = (int)__builtin_ctzll(tmsk);
    lx = __uint_as_float((unsigned)__builtin_amdgcn_readlane(__float_as_int(sxy.x), bwl));
    ly = __uint_as_float((unsigned)__builtin_amdgcn_readlane(__float_as_int(sxy.y), bwl));
    lz = __uint_as_float((unsigned)__builtin_amdgcn_readlane(__float_as_int(sgz), bwl));
    // one barrier/iter: parity double-buffer makes overwrite-while-read impossible
  }
}

// ---------------- Ball query ----------------
__global__ __launch_bounds__(256)
void ballq_kernel(const float* __restrict__ xyz, const int* __restrict__ fps_idx,
                  int* __restrict__ ball_idx)
{
#pragma clang fp contract(off)
  const int gw = (int)((blockIdx.x * blockDim.x + threadIdx.x) >> 6);
  const int lane = threadIdx.x & 63;
  const int b = gw >> 10, s = gw & 1023;
  const float* __restrict__ X = xyz + (size_t)b * NPTS * 3;
  const int ci = fps_idx[b * NP + s];
  const float cx = X[ci * 3 + 0], cy = X[ci * 3 + 1], cz = X[ci * 3 + 2];
  const float n2 = ((cx * cx) + (cy * cy)) + (cz * cz);
  int* __restrict__ out = ball_idx + (size_t)(b * NP + s) * NS;

  int cnt = 0;
  int first = -1;
  for (int c0 = 0; c0 < NPTS && cnt < NS; c0 += 64) {
    const int p = c0 + lane;
    const float x = X[p * 3 + 0], y = X[p * 3 + 1], z = X[p * 3 + 2];
    const float x2 = ((x * x) + (y * y)) + (z * z);
    const float dt = ((cx * x) + (cy * y)) + (cz * z);
    const float d2 = (n2 + x2) - (2.0f * dt);
    const bool inball = d2 < 0.04f;
    const unsigned long long mm = __ballot(inball);
    if (inball) {
      const int pos = cnt + __popcll(mm & ((1ull << lane) - 1ull));
      if (pos < NS) out[pos] = p;
    }
    if (first < 0 && mm != 0ull) first = c0 + __builtin_ctzll(mm);
    cnt += __popcll(mm);
  }
  if (cnt < NS) {
    if (first < 0) first = 0;
    if (lane >= cnt && lane < NS) out[lane] = first;
  }
}

// ---------------- Transpose feats [B][C][N] -> [B][N][C] ----------------
__global__ __launch_bounds__(256)
void transpose_kernel(const float* __restrict__ feats, float* __restrict__ featsT)
{
  __shared__ float t[32][33];
  const int b = blockIdx.z;
  const int cb = blockIdx.y * 32;
  const int nb = blockIdx.x * 32;
  const int tx = threadIdx.x;
  const int ty = threadIdx.y;
  const float* __restrict__ F = feats + (size_t)b * CIN * NPTS;
#pragma unroll
  for (int i = 0; i < 32; i += 8)
    t[ty + i][tx] = F[(size_t)(cb + ty + i) * NPTS + nb + tx];
  __syncthreads();
  float* __restrict__ FT_ = featsT + (size_t)b * NPTS * CIN;
#pragma unroll
  for (int i = 0; i < 32; i += 8)
    FT_[(size_t)(nb + ty + i) * CIN + cb + tx] = t[tx][ty + i];
}

// ---------------- Gather + max-pool ----------------
__global__ __launch_bounds__(128)
void pool_kernel(const float* __restrict__ featsT, const int* __restrict__ ball_idx,
                 float* __restrict__ pooled)
{
  const int bs = blockIdx.x;
  const int c = threadIdx.x;
  const int b = bs >> 10;
  const int* __restrict__ idx = ball_idx + (size_t)bs * NS;
  const float* __restrict__ FT_ = featsT + (size_t)b * NPTS * CIN;
  float m = -INFINITY;
#pragma unroll 4
  for (int k = 0; k < NS; ++k) {
    const int n = idx[k];
    m = fmaxf(m, FT_[(size_t)n * CIN + c]);
  }
  pooled[(size_t)bs * CIN + c] = m;
}

// ---------------- 1x1 conv + BN + LeakyReLU ----------------
#define GO 128
#define GS 64
__global__ __launch_bounds__(256, 1)
void gemm_kernel(const float* __restrict__ pooled, const float* __restrict__ W,
                 const float* __restrict__ gamma, const float* __restrict__ beta,
                 const float* __restrict__ mean, const float* __restrict__ var,
                 float* __restrict__ out)
{
  __shared__ float Wt[128 * 132];
  __shared__ float Pl[128 * 68];
  const int b = blockIdx.z;
  const int ob = blockIdx.y * GO;
  const int sb = blockIdx.x * GS;
  const int tid = threadIdx.x;

  for (int i = tid; i < GO * 128; i += 256) {
    const int o = i >> 7, c = i & 127;
    Wt[c * 132 + o] = W[(ob + o) * 128 + c];
  }
  const float* __restrict__ P = pooled + (size_t)(b * NP + sb) * 128;
  for (int i = tid; i < GS * 128; i += 256) {
    const int s = i >> 7, c = i & 127;
    Pl[c * 68 + s] = P[s * 128 + c];
  }
  __syncthreads();

  const int to = tid & 31, ts = tid >> 5;
  const int o0 = to * 4, s0 = ts * 8;
  float acc[4][8];
#pragma unroll
  for (int o = 0; o < 4; ++o)
#pragma unroll
    for (int j = 0; j < 8; ++j) acc[o][j] = 0.0f;

  for (int c = 0; c < 128; ++c) {
    const float4 wv = *(const float4*)&Wt[c * 132 + o0];
    const float4 pa = *(const float4*)&Pl[c * 68 + s0];
    const float4 pb = *(const float4*)&Pl[c * 68 + s0 + 4];
    const float wr[4] = {wv.x, wv.y, wv.z, wv.w};
    const float pr[8] = {pa.x, pa.y, pa.z, pa.w, pb.x, pb.y, pb.z, pb.w};
#pragma unroll
    for (int o = 0; o < 4; ++o)
#pragma unroll
      for (int j = 0; j < 8; ++j)
        acc[o][j] = fmaf(wr[o], pr[j], acc[o][j]);
  }

#pragma unroll
  for (int o = 0; o < 4; ++o) {
    const int oo = ob + o0 + o;
    const float sc = gamma[oo] / sqrtf(var[oo] + 1e-5f);
    const float sh = beta[oo] - mean[oo] * sc;
    float r[8];
#pragma unroll
    for (int j = 0; j < 8; ++j) {
      const float y = fmaf(acc[o][j], sc, sh);
      r[j] = (y >= 0.0f) ? y : 0.2f * y;
    }
    float* __restrict__ O = out + (size_t)(b * COUT + oo) * NP + sb + s0;
    *(float4*)&O[0] = make_float4(r[0], r[1], r[2], r[3]);
    *(float4*)&O[4] = make_float4(r[4], r[5], r[6], r[7]);
  }
}

// ---------------- launch ----------------
extern "C" void kernel_launch(void* const* d_in, const int* in_sizes, int n_in,
                              void* d_out, int out_size, void* d_ws, size_t ws_size,
                              hipStream_t stream)
{
  (void)in_sizes; (void)n_in; (void)out_size; (void)ws_size;
  const float* xyz   = (const float*)d_in[0];
  const float* feats = (const float*)d_in[1];
  const float* W     = (const float*)d_in[2];
  const float* gamma = (const float*)d_in[3];
  const float* beta  = (const float*)d_in[4];
  const float* mean  = (const float*)d_in[5];
  const float* var   = (const float*)d_in[6];
  float* out = (float*)d_out;

  char* ws = (char*)d_ws;
  // fps_idx [32KB] @0 | ball_idx [1MB] @32768 | featsT [64MB] @1081344 |
  // pooled [4MB] @68190208. Sort scratch aliases featsT head (dead before
  // transpose runs; stream order guarantees no overlap-in-time).
  int*   fps_idx  = (int*)(ws + 0);
  int*   ball_idx = (int*)(ws + 32768);
  char*  fbase    = ws + 1081344;
  float* featsT   = (float*)fbase;
  float* pooled   = (float*)(ws + 68190208);

  float2* sxy2S  = (float2*)(fbase + 0);        // 1 MB
  float*  szS    = (float*)(fbase + 1048576);   // 512 KB
  int*    siS    = (int*)(fbase + 1572864);     // 512 KB
  int*    hist   = (int*)(fbase + 2097152);     // 16 KB
  int*    cursor = (int*)(fbase + 2113536);     // 16 KB

  zero_hist_kernel<<<NBATCH, NCELL, 0, stream>>>(hist);
  hist_kernel<<<(NBATCH * NPTS) / 256, 256, 0, stream>>>(xyz, hist);
  scan_kernel<<<NBATCH, NCELL, 0, stream>>>(hist, cursor);
  scatter_kernel<<<(NBATCH * NPTS) / 256, 256, 0, stream>>>(xyz, cursor, sxy2S, szS, siS);
  fps_kernel<<<NBATCH, FPS_T, 0, stream>>>(xyz, sxy2S, szS, siS, fps_idx);
  ballq_kernel<<<(NBATCH * NP) / 4, 256, 0, stream>>>(xyz, fps_idx, ball_idx);
  transpose_kernel<<<dim3(NPTS / 32, CIN / 32, NBATCH), dim3(32, 8), 0, stream>>>(feats, featsT);
  pool_kernel<<<NBATCH * NP, CIN, 0, stream>>>(featsT, ball_idx, pooled);
  gemm_kernel<<<dim3(NP / GS, COUT / GO, NBATCH), 256, 0, stream>>>(pooled, W, gamma, beta, mean, var, out);
}

// Round 10
// 1853.889 us; speedup vs baseline: 1.3523x; 1.3523x over previous
//
#include <hip/hip_runtime.h>
#include <math.h>

#define NPTS 16384
#define NBATCH 8
#define CIN 128
#define COUT 256
#define NP 1024
#define NS 32

#define NCELL 512     // 8x8x8 Morton cells
#define FPS_T 1024    // 16 waves

// ---------------- spatial sort preprocessing ----------------
__device__ __forceinline__ int cell_of(float x, float y, float z)
{
  int ix = (int)(x * 8.0f); ix = ix < 0 ? 0 : (ix > 7 ? 7 : ix);
  int iy = (int)(y * 8.0f); iy = iy < 0 ? 0 : (iy > 7 ? 7 : iy);
  int iz = (int)(z * 8.0f); iz = iz < 0 ? 0 : (iz > 7 ? 7 : iz);
  int m = 0;
#pragma unroll
  for (int b = 0; b < 3; ++b)
    m |= (((ix >> b) & 1) << (3 * b)) | (((iy >> b) & 1) << (3 * b + 1))
       | (((iz >> b) & 1) << (3 * b + 2));
  return m;
}

__global__ void zero_hist_kernel(int* __restrict__ hist)
{
  hist[blockIdx.x * NCELL + threadIdx.x] = 0;
}

__global__ void hist_kernel(const float* __restrict__ xyz, int* __restrict__ hist)
{
  const int i = blockIdx.x * 256 + threadIdx.x;
  const int b = i >> 14, n = i & (NPTS - 1);
  const float* p = xyz + ((size_t)b * NPTS + n) * 3;
  atomicAdd(&hist[b * NCELL + cell_of(p[0], p[1], p[2])], 1);
}

__global__ void scan_kernel(const int* __restrict__ hist, int* __restrict__ cursor)
{
  __shared__ int s[NCELL];
  const int b = blockIdx.x, t = threadIdx.x;
  const int h = hist[b * NCELL + t];
  s[t] = h;
  __syncthreads();
  for (int off = 1; off < NCELL; off <<= 1) {
    const int v = (t >= off) ? s[t - off] : 0;
    __syncthreads();
    s[t] += v;
    __syncthreads();
  }
  cursor[b * NCELL + t] = s[t] - h;   // exclusive
}

__global__ void scatter_kernel(const float* __restrict__ xyz, int* __restrict__ cursor,
                               float2* __restrict__ sxy2S, float* __restrict__ szS,
                               int* __restrict__ siS)
{
  const int i = blockIdx.x * 256 + threadIdx.x;
  const int b = i >> 14, n = i & (NPTS - 1);
  const float* p = xyz + ((size_t)b * NPTS + n) * 3;
  const float x = p[0], y = p[1], z = p[2];
  const int pos = atomicAdd(&cursor[b * NCELL + cell_of(x, y, z)], 1);
  const size_t o = (size_t)b * NPTS + pos;
  sxy2S[o] = make_float2(x, y);
  szS[o] = z;
  siS[o] = n;
}

// ---------------- DPP helpers ----------------
template <int CTRL>
__device__ __forceinline__ void dpp_max64(unsigned& hi, unsigned& lo)
{
  const unsigned ohi = (unsigned)__builtin_amdgcn_update_dpp((int)hi, (int)hi, CTRL, 0xF, 0xF, false);
  const unsigned olo = (unsigned)__builtin_amdgcn_update_dpp((int)lo, (int)lo, CTRL, 0xF, 0xF, false);
  const bool t = (ohi > hi) || (ohi == hi && olo > lo);
  hi = t ? ohi : hi;
  lo = t ? olo : lo;
}
template <int CTRL>
__device__ __forceinline__ float dppmaxf(float v)
{
  const float o = __uint_as_float((unsigned)__builtin_amdgcn_update_dpp(
      (int)__float_as_uint(v), (int)__float_as_uint(v), CTRL, 0xF, 0xF, false));
  return fmaxf(v, o);
}
template <int CTRL>
__device__ __forceinline__ float dppminf(float v)
{
  const float o = __uint_as_float((unsigned)__builtin_amdgcn_update_dpp(
      (int)__float_as_uint(v), (int)__float_as_uint(v), CTRL, 0xF, 0xF, false));
  return fminf(v, o);
}
template <int CTRL>
__device__ __forceinline__ unsigned dppmaxu(unsigned v)
{
  const unsigned o = (unsigned)__builtin_amdgcn_update_dpp((int)v, (int)v, CTRL, 0xF, 0xF, false);
  return v > o ? v : o;
}
#define RED6F(v) v = dppmaxf<0x111>(v); v = dppmaxf<0x112>(v); v = dppmaxf<0x114>(v); \
                 v = dppmaxf<0x118>(v); v = dppmaxf<0x142>(v); v = dppmaxf<0x143>(v);
#define RED6FN(v) v = dppminf<0x111>(v); v = dppminf<0x112>(v); v = dppminf<0x114>(v); \
                  v = dppminf<0x118>(v); v = dppminf<0x142>(v); v = dppminf<0x143>(v);
#define RED6U(v) v = dppmaxu<0x111>(v); v = dppmaxu<0x112>(v); v = dppmaxu<0x114>(v); \
                 v = dppmaxu<0x118>(v); v = dppmaxu<0x142>(v); v = dppmaxu<0x143>(v);

// ---------------- FPS ----------------
// 1 block/batch, 1024 thr (16 waves). INTERLEAVED ownership: thread t owns
// sorted points {s*1024+t}; wave w owns tiles {s*16+w} (64 consecutive Morton
// points each) -> the spatially-clustered active tiles spread across waves
// (round 9 concentrated them on one wave; its per-tile DPP chains also
// serialized -> regression). Per iter: lane-parallel tile tests vs the wave's
// cached max (exact upper bound) -> ballot -> SGPR mask -> 16 s_cbranch
// update blocks (10 ops, NO cross-lane) -> ONE rescan (15 fmax + RED6F +
// tie-select + RED6U) per active wave. Winner z broadcast through LDS redz
// (removes the per-iter exposed global load from the combine).
__global__ __launch_bounds__(FPS_T)
void fps_kernel(const float* __restrict__ xyz,
                const float2* __restrict__ sxy2S, const float* __restrict__ szS,
                const int* __restrict__ siS, int* __restrict__ fps_idx)
{
#pragma clang fp contract(off)
  __shared__ float2 XY[NPTS];                   // 128 KB, sorted order
  __shared__ unsigned long long redk[2][16];
  __shared__ float redz[2][16];
  __shared__ float tb[16][16][6];               // [wave][slot] tile bboxes
  const int b = blockIdx.x;
  const int t = threadIdx.x;
  const int lane = t & 63, w = t >> 6;
  const int j16 = lane & 15;
  const float* __restrict__ X = xyz + (size_t)b * NPTS * 3;
  const float* __restrict__ ZS = szS + (size_t)b * NPTS;
  const int* __restrict__ IS = siS + (size_t)b * NPTS;
  const float2* __restrict__ XYS = sxy2S + (size_t)b * NPTS;

  float z[16], dist[16];
  unsigned pl[16];
#pragma unroll
  for (int s = 0; s < 16; ++s) {
    const int sp = (s << 10) + t;               // sorted pos owned by (s, t)
    const float2 v = XYS[sp];                   // coalesced
    XY[sp] = v;                                 // conflict-free ds_write_b64
    z[s] = ZS[sp];
    pl[s] = ((unsigned)(IS[sp] ^ 0x3FFF) << 14) | (unsigned)sp;
    dist[s] = 1e10f;
    // tile (s*16+w) bbox: reduce over this wave's 64 lanes (init-only)
    float xn = v.x, xx = v.x, yn = v.y, yx = v.y, zn = z[s], zx = z[s];
    RED6FN(xn) RED6F(xx) RED6FN(yn) RED6F(yx) RED6FN(zn) RED6F(zx)
    if (lane == 63) {
      tb[w][s][0] = xn; tb[w][s][1] = xx; tb[w][s][2] = yn;
      tb[w][s][3] = yx; tb[w][s][4] = zn; tb[w][s][5] = zx;
    }
  }
  __syncthreads();
  const float bxn = tb[w][j16][0], bxx = tb[w][j16][1];
  const float byn = tb[w][j16][2], byx = tb[w][j16][3];
  const float bzn = tb[w][j16][4], bzx = tb[w][j16][5];

  unsigned wkh = __float_as_uint(1e10f), wkl = 0;  // cached wave key
  float zc = 0.0f;                                  // cached winner z
  int cur = 0;
  float lx = X[0], ly = X[1], lz = X[2];

  for (int k = 0; k < NP; ++k) {
    if (t == 0) fps_idx[b * NP + k] = cur;

    // lane j16 tests tile j16*16+w: exact conservative skip vs cached wave max
    const float ddx = fmaxf(fmaxf(bxn - lx, lx - bxx), 0.0f);
    const float ddy = fmaxf(fmaxf(byn - ly, ly - byx), 0.0f);
    const float ddz = fmaxf(fmaxf(bzn - lz, lz - bzx), 0.0f);
    const float db2 = ((ddx * ddx) + (ddy * ddy)) + (ddz * ddz);
    const bool act = db2 <= __uint_as_float(wkh) * 1.00001f;
    const unsigned msk = __builtin_amdgcn_readfirstlane(
        (unsigned)__ballot(act) & 0xFFFFu);

    if (msk) {
      // updates only for active tiles: 10 ops, lane-parallel, no cross-lane
#define UPD(J) if (msk & (1u << (J))) {                                  \
        const float2 v = XY[((J) << 10) + t];                            \
        const float dx = v.x - lx, dy = v.y - ly, dz = z[(J)] - lz;      \
        const float d = ((dx * dx) + (dy * dy)) + (dz * dz);             \
        dist[(J)] = fminf(dist[(J)], d); }
      UPD(0)  UPD(1)  UPD(2)  UPD(3)  UPD(4)  UPD(5)  UPD(6)  UPD(7)
      UPD(8)  UPD(9)  UPD(10) UPD(11) UPD(12) UPD(13) UPD(14) UPD(15)
#undef UPD
      // single rescan per active wave
      float lmax = dist[0];
#pragma unroll
      for (int s = 1; s < 16; ++s) lmax = fmaxf(lmax, dist[s]);
      RED6F(lmax)
      const unsigned mh = (unsigned)__builtin_amdgcn_readlane(__float_as_int(lmax), 63);
      unsigned cd = 0;
#pragma unroll
      for (int s = 0; s < 16; ++s)
        cd = (__float_as_uint(dist[s]) == mh && pl[s] > cd) ? pl[s] : cd;
      RED6U(cd)
      const unsigned sl = (unsigned)__builtin_amdgcn_readlane((int)cd, 63);
      // winner z broadcast (winner is in this wave by construction)
      float zm = 0.0f;
      bool have = false;
#pragma unroll
      for (int s = 0; s < 16; ++s) {
        const bool c2 = (__float_as_uint(dist[s]) == mh) && (pl[s] == sl);
        zm = c2 ? z[s] : zm;
        have = have || c2;
      }
      const unsigned long long hm = __ballot(have);
      zc = __uint_as_float((unsigned)__builtin_amdgcn_readlane(
          __float_as_int(zm), (int)__builtin_ctzll(hm)));
      wkh = mh; wkl = sl;
    }
    const int p = k & 1;
    if (lane == 0) {
      redk[p][w] = ((unsigned long long)wkh << 32) | wkl;
      redz[p][w] = zc;
    }
    __syncthreads();

    // cross-wave combine: LDS-only speculative winner loads + 4-step DPP
    const unsigned long long kj = redk[p][j16];
    const unsigned shi = (unsigned)(kj >> 32), slo = (unsigned)kj;
    const int sposj = (int)(slo & 0x3FFFu);
    const float2 sxy = XY[sposj];               // LDS direct (sorted layout)
    const float szv = redz[p][j16];             // LDS
    unsigned h2 = shi, l3 = slo;
    dpp_max64<0x111>(h2, l3);
    dpp_max64<0x112>(h2, l3);
    dpp_max64<0x114>(h2, l3);
    dpp_max64<0x118>(h2, l3);                   // lane 15 of each row = global max
    const unsigned kmh = (unsigned)__builtin_amdgcn_readlane((int)h2, 15);
    const unsigned kml = (unsigned)__builtin_amdgcn_readlane((int)l3, 15);
    cur = (int)((kml >> 14) & 0x3FFFu) ^ 0x3FFF;
    const unsigned long long tmsk = __ballot(shi == kmh && slo == kml) & 0xFFFFull;
    const int bwl = (int)__builtin_ctzll(tmsk);
    lx = __uint_as_float((unsigned)__builtin_amdgcn_readlane(__float_as_int(sxy.x), bwl));
    ly = __uint_as_float((unsigned)__builtin_amdgcn_readlane(__float_as_int(sxy.y), bwl));
    lz = __uint_as_float((unsigned)__builtin_amdgcn_readlane(__float_as_int(szv), bwl));
    // one barrier/iter: parity double-buffer makes overwrite-while-read impossible
  }
}

// ---------------- Ball query ----------------
__global__ __launch_bounds__(256)
void ballq_kernel(const float* __restrict__ xyz, const int* __restrict__ fps_idx,
                  int* __restrict__ ball_idx)
{
#pragma clang fp contract(off)
  const int gw = (int)((blockIdx.x * blockDim.x + threadIdx.x) >> 6);
  const int lane = threadIdx.x & 63;
  const int b = gw >> 10, s = gw & 1023;
  const float* __restrict__ X = xyz + (size_t)b * NPTS * 3;
  const int ci = fps_idx[b * NP + s];
  const float cx = X[ci * 3 + 0], cy = X[ci * 3 + 1], cz = X[ci * 3 + 2];
  const float n2 = ((cx * cx) + (cy * cy)) + (cz * cz);
  int* __restrict__ out = ball_idx + (size_t)(b * NP + s) * NS;

  int cnt = 0;
  int first = -1;
  for (int c0 = 0; c0 < NPTS && cnt < NS; c0 += 64) {
    const int p = c0 + lane;
    const float x = X[p * 3 + 0], y = X[p * 3 + 1], z = X[p * 3 + 2];
    const float x2 = ((x * x) + (y * y)) + (z * z);
    const float dt = ((cx * x) + (cy * y)) + (cz * z);
    const float d2 = (n2 + x2) - (2.0f * dt);
    const bool inball = d2 < 0.04f;
    const unsigned long long mm = __ballot(inball);
    if (inball) {
      const int pos = cnt + __popcll(mm & ((1ull << lane) - 1ull));
      if (pos < NS) out[pos] = p;
    }
    if (first < 0 && mm != 0ull) first = c0 + __builtin_ctzll(mm);
    cnt += __popcll(mm);
  }
  if (cnt < NS) {
    if (first < 0) first = 0;
    if (lane >= cnt && lane < NS) out[lane] = first;
  }
}

// ---------------- Transpose feats [B][C][N] -> [B][N][C] ----------------
__global__ __launch_bounds__(256)
void transpose_kernel(const float* __restrict__ feats, float* __restrict__ featsT)
{
  __shared__ float t[32][33];
  const int b = blockIdx.z;
  const int cb = blockIdx.y * 32;
  const int nb = blockIdx.x * 32;
  const int tx = threadIdx.x;
  const int ty = threadIdx.y;
  const float* __restrict__ F = feats + (size_t)b * CIN * NPTS;
#pragma unroll
  for (int i = 0; i < 32; i += 8)
    t[ty + i][tx] = F[(size_t)(cb + ty + i) * NPTS + nb + tx];
  __syncthreads();
  float* __restrict__ FT_ = featsT + (size_t)b * NPTS * CIN;
#pragma unroll
  for (int i = 0; i < 32; i += 8)
    FT_[(size_t)(nb + ty + i) * CIN + cb + tx] = t[tx][ty + i];
}

// ---------------- Gather + max-pool ----------------
__global__ __launch_bounds__(128)
void pool_kernel(const float* __restrict__ featsT, const int* __restrict__ ball_idx,
                 float* __restrict__ pooled)
{
  const int bs = blockIdx.x;
  const int c = threadIdx.x;
  const int b = bs >> 10;
  const int* __restrict__ idx = ball_idx + (size_t)bs * NS;
  const float* __restrict__ FT_ = featsT + (size_t)b * NPTS * CIN;
  float m = -INFINITY;
#pragma unroll 4
  for (int k = 0; k < NS; ++k) {
    const int n = idx[k];
    m = fmaxf(m, FT_[(size_t)n * CIN + c]);
  }
  pooled[(size_t)bs * CIN + c] = m;
}

// ---------------- 1x1 conv + BN + LeakyReLU ----------------
#define GO 128
#define GS 64
__global__ __launch_bounds__(256, 1)
void gemm_kernel(const float* __restrict__ pooled, const float* __restrict__ W,
                 const float* __restrict__ gamma, const float* __restrict__ beta,
                 const float* __restrict__ mean, const float* __restrict__ var,
                 float* __restrict__ out)
{
  __shared__ float Wt[128 * 132];
  __shared__ float Pl[128 * 68];
  const int b = blockIdx.z;
  const int ob = blockIdx.y * GO;
  const int sb = blockIdx.x * GS;
  const int tid = threadIdx.x;

  for (int i = tid; i < GO * 128; i += 256) {
    const int o = i >> 7, c = i & 127;
    Wt[c * 132 + o] = W[(ob + o) * 128 + c];
  }
  const float* __restrict__ P = pooled + (size_t)(b * NP + sb) * 128;
  for (int i = tid; i < GS * 128; i += 256) {
    const int s = i >> 7, c = i & 127;
    Pl[c * 68 + s] = P[s * 128 + c];
  }
  __syncthreads();

  const int to = tid & 31, ts = tid >> 5;
  const int o0 = to * 4, s0 = ts * 8;
  float acc[4][8];
#pragma unroll
  for (int o = 0; o < 4; ++o)
#pragma unroll
    for (int j = 0; j < 8; ++j) acc[o][j] = 0.0f;

  for (int c = 0; c < 128; ++c) {
    const float4 wv = *(const float4*)&Wt[c * 132 + o0];
    const float4 pa = *(const float4*)&Pl[c * 68 + s0];
    const float4 pb = *(const float4*)&Pl[c * 68 + s0 + 4];
    const float wr[4] = {wv.x, wv.y, wv.z, wv.w};
    const float pr[8] = {pa.x, pa.y, pa.z, pa.w, pb.x, pb.y, pb.z, pb.w};
#pragma unroll
    for (int o = 0; o < 4; ++o)
#pragma unroll
      for (int j = 0; j < 8; ++j)
        acc[o][j] = fmaf(wr[o], pr[j], acc[o][j]);
  }

#pragma unroll
  for (int o = 0; o < 4; ++o) {
    const int oo = ob + o0 + o;
    const float sc = gamma[oo] / sqrtf(var[oo] + 1e-5f);
    const float sh = beta[oo] - mean[oo] * sc;
    float r[8];
#pragma unroll
    for (int j = 0; j < 8; ++j) {
      const float y = fmaf(acc[o][j], sc, sh);
      r[j] = (y >= 0.0f) ? y : 0.2f * y;
    }
    float* __restrict__ O = out + (size_t)(b * COUT + oo) * NP + sb + s0;
    *(float4*)&O[0] = make_float4(r[0], r[1], r[2], r[3]);
    *(float4*)&O[4] = make_float4(r[4], r[5], r[6], r[7]);
  }
}

// ---------------- launch ----------------
extern "C" void kernel_launch(void* const* d_in, const int* in_sizes, int n_in,
                              void* d_out, int out_size, void* d_ws, size_t ws_size,
                              hipStream_t stream)
{
  (void)in_sizes; (void)n_in; (void)out_size; (void)ws_size;
  const float* xyz   = (const float*)d_in[0];
  const float* feats = (const float*)d_in[1];
  const float* W     = (const float*)d_in[2];
  const float* gamma = (const float*)d_in[3];
  const float* beta  = (const float*)d_in[4];
  const float* mean  = (const float*)d_in[5];
  const float* var   = (const float*)d_in[6];
  float* out = (float*)d_out;

  char* ws = (char*)d_ws;
  // fps_idx [32KB] @0 | ball_idx [1MB] @32768 | featsT [64MB] @1081344 |
  // pooled [4MB] @68190208. Sort scratch aliases featsT head (dead before
  // transpose runs; stream order guarantees no overlap-in-time).
  int*   fps_idx  = (int*)(ws + 0);
  int*   ball_idx = (int*)(ws + 32768);
  char*  fbase    = ws + 1081344;
  float* featsT   = (float*)fbase;
  float* pooled   = (float*)(ws + 68190208);

  float2* sxy2S  = (float2*)(fbase + 0);        // 1 MB
  float*  szS    = (float*)(fbase + 1048576);   // 512 KB
  int*    siS    = (int*)(fbase + 1572864);     // 512 KB
  int*    hist   = (int*)(fbase + 2097152);     // 16 KB
  int*    cursor = (int*)(fbase + 2113536);     // 16 KB

  zero_hist_kernel<<<NBATCH, NCELL, 0, stream>>>(hist);
  hist_kernel<<<(NBATCH * NPTS) / 256, 256, 0, stream>>>(xyz, hist);
  scan_kernel<<<NBATCH, NCELL, 0, stream>>>(hist, cursor);
  scatter_kernel<<<(NBATCH * NPTS) / 256, 256, 0, stream>>>(xyz, cursor, sxy2S, szS, siS);
  fps_kernel<<<NBATCH, FPS_T, 0, stream>>>(xyz, sxy2S, szS, siS, fps_idx);
  ballq_kernel<<<(NBATCH * NP) / 4, 256, 0, stream>>>(xyz, fps_idx, ball_idx);
  transpose_kernel<<<dim3(NPTS / 32, CIN / 32, NBATCH), dim3(32, 8), 0, stream>>>(feats, featsT);
  pool_kernel<<<NBATCH * NP, CIN, 0, stream>>>(featsT, ball_idx, pooled);
  gemm_kernel<<<dim3(NP / GS, COUT / GO, NBATCH), 256, 0, stream>>>(pooled, W, gamma, beta, mean, var, out);
}

// Round 11
// 1843.990 us; speedup vs baseline: 1.3596x; 1.0054x over previous
//
#include <hip/hip_runtime.h>
#include <math.h>

#define NPTS 16384
#define NBATCH 8
#define CIN 128
#define COUT 256
#define NP 1024
#define NS 32

#define NCELL 512     // 8x8x8 Morton cells
#define FPS_T 1024    // 16 waves

// ---------------- spatial sort preprocessing ----------------
__device__ __forceinline__ int cell_of(float x, float y, float z)
{
  int ix = (int)(x * 8.0f); ix = ix < 0 ? 0 : (ix > 7 ? 7 : ix);
  int iy = (int)(y * 8.0f); iy = iy < 0 ? 0 : (iy > 7 ? 7 : iy);
  int iz = (int)(z * 8.0f); iz = iz < 0 ? 0 : (iz > 7 ? 7 : iz);
  int m = 0;
#pragma unroll
  for (int b = 0; b < 3; ++b)
    m |= (((ix >> b) & 1) << (3 * b)) | (((iy >> b) & 1) << (3 * b + 1))
       | (((iz >> b) & 1) << (3 * b + 2));
  return m;
}

__global__ void zero_hist_kernel(int* __restrict__ hist)
{
  hist[blockIdx.x * NCELL + threadIdx.x] = 0;
}

__global__ void hist_kernel(const float* __restrict__ xyz, int* __restrict__ hist)
{
  const int i = blockIdx.x * 256 + threadIdx.x;
  const int b = i >> 14, n = i & (NPTS - 1);
  const float* p = xyz + ((size_t)b * NPTS + n) * 3;
  atomicAdd(&hist[b * NCELL + cell_of(p[0], p[1], p[2])], 1);
}

__global__ void scan_kernel(const int* __restrict__ hist, int* __restrict__ cursor)
{
  __shared__ int s[NCELL];
  const int b = blockIdx.x, t = threadIdx.x;
  const int h = hist[b * NCELL + t];
  s[t] = h;
  __syncthreads();
  for (int off = 1; off < NCELL; off <<= 1) {
    const int v = (t >= off) ? s[t - off] : 0;
    __syncthreads();
    s[t] += v;
    __syncthreads();
  }
  cursor[b * NCELL + t] = s[t] - h;   // exclusive
}

__global__ void scatter_kernel(const float* __restrict__ xyz, int* __restrict__ cursor,
                               float2* __restrict__ sxy2S, float* __restrict__ szS,
                               int* __restrict__ siS)
{
  const int i = blockIdx.x * 256 + threadIdx.x;
  const int b = i >> 14, n = i & (NPTS - 1);
  const float* p = xyz + ((size_t)b * NPTS + n) * 3;
  const float x = p[0], y = p[1], z = p[2];
  const int pos = atomicAdd(&cursor[b * NCELL + cell_of(x, y, z)], 1);
  const size_t o = (size_t)b * NPTS + pos;
  sxy2S[o] = make_float2(x, y);
  szS[o] = z;
  siS[o] = n;
}

// ---------------- DPP helpers ----------------
template <int CTRL>
__device__ __forceinline__ void dpp_max64(unsigned& hi, unsigned& lo)
{
  const unsigned ohi = (unsigned)__builtin_amdgcn_update_dpp((int)hi, (int)hi, CTRL, 0xF, 0xF, false);
  const unsigned olo = (unsigned)__builtin_amdgcn_update_dpp((int)lo, (int)lo, CTRL, 0xF, 0xF, false);
  const bool t = (ohi > hi) || (ohi == hi && olo > lo);
  hi = t ? ohi : hi;
  lo = t ? olo : lo;
}
template <int CTRL>
__device__ __forceinline__ float dppmaxf(float v)
{
  const float o = __uint_as_float((unsigned)__builtin_amdgcn_update_dpp(
      (int)__float_as_uint(v), (int)__float_as_uint(v), CTRL, 0xF, 0xF, false));
  return fmaxf(v, o);
}
template <int CTRL>
__device__ __forceinline__ float dppminf(float v)
{
  const float o = __uint_as_float((unsigned)__builtin_amdgcn_update_dpp(
      (int)__float_as_uint(v), (int)__float_as_uint(v), CTRL, 0xF, 0xF, false));
  return fminf(v, o);
}
#define RED6F(v) v = dppmaxf<0x111>(v); v = dppmaxf<0x112>(v); v = dppmaxf<0x114>(v); \
                 v = dppmaxf<0x118>(v); v = dppmaxf<0x142>(v); v = dppmaxf<0x143>(v);
#define RED6FN(v) v = dppminf<0x111>(v); v = dppminf<0x112>(v); v = dppminf<0x114>(v); \
                  v = dppminf<0x118>(v); v = dppminf<0x142>(v); v = dppminf<0x143>(v);
#define RED64(h, l) dpp_max64<0x111>(h, l); dpp_max64<0x112>(h, l); \
                    dpp_max64<0x114>(h, l); dpp_max64<0x118>(h, l); \
                    dpp_max64<0x142>(h, l); dpp_max64<0x143>(h, l);

// ---------------- FPS ----------------
// 1 block/batch, 1024 thr (16 waves, pinned 4 waves/EU). Interleaved tile
// ownership: thread t owns sorted points {s*1024+t}; tile (s,w) = 64
// consecutive Morton points. Per-tile EXACT u64 keys (maxdist|invpid|spos)
// cached in LDS tkL[w][s]; recomputed ONLY when the tile updates (fused RED6
// into the update — kills round-10's 130-op per-wave rescan). Tile test reads
// the tile's OWN cached max (tighter than round-10's wave max). Wave key =
// dpp4 over 16 LDS tile keys, cached when wave inactive. Tie-break exact
// everywhere (max invpid = min original idx). 1 barrier/iter, parity slots.
__global__ __launch_bounds__(FPS_T)
__attribute__((amdgpu_waves_per_eu(4, 4)))
void fps_kernel(const float* __restrict__ xyz,
                const float2* __restrict__ sxy2S, const float* __restrict__ szS,
                const int* __restrict__ siS, int* __restrict__ fps_idx)
{
#pragma clang fp contract(off)
  __shared__ float2 XY[NPTS];                   // 128 KB, sorted order
  __shared__ unsigned long long redk[2][16];
  __shared__ unsigned long long tkL[16][16];    // [wave][slot] tile keys
  __shared__ float tb[16][16][6];               // [wave][slot] tile bboxes
  const int b = blockIdx.x;
  const int t = threadIdx.x;
  const int lane = t & 63, w = t >> 6;
  const int j16 = lane & 15;
  const float* __restrict__ X = xyz + (size_t)b * NPTS * 3;
  const float* __restrict__ ZS = szS + (size_t)b * NPTS;
  const int* __restrict__ IS = siS + (size_t)b * NPTS;
  const float2* __restrict__ XYS = sxy2S + (size_t)b * NPTS;

  float z[16], dist[16];
  unsigned pl[16];
#pragma unroll
  for (int s = 0; s < 16; ++s) {
    const int sp = (s << 10) + t;               // sorted pos owned by (s, t)
    const float2 v = XYS[sp];                   // coalesced
    XY[sp] = v;                                 // conflict-free ds_write_b64
    z[s] = ZS[sp];
    pl[s] = ((unsigned)(IS[sp] ^ 0x3FFF) << 14) | (unsigned)sp;
    dist[s] = 1e10f;
    // tile (s,w) bbox + initial key (dist uniform 1e10 -> key = max pl)
    float xn = v.x, xx = v.x, yn = v.y, yx = v.y, zn = z[s], zx = z[s];
    RED6FN(xn) RED6F(xx) RED6FN(yn) RED6F(yx) RED6FN(zn) RED6F(zx)
    unsigned kh0 = __float_as_uint(1e10f), kl0 = pl[s];
    RED64(kh0, kl0)
    if (lane == 63) {
      tb[w][s][0] = xn; tb[w][s][1] = xx; tb[w][s][2] = yn;
      tb[w][s][3] = yx; tb[w][s][4] = zn; tb[w][s][5] = zx;
      tkL[w][s] = ((unsigned long long)kh0 << 32) | kl0;
    }
  }
  __syncthreads();
  const float bxn = tb[w][j16][0], bxx = tb[w][j16][1];
  const float byn = tb[w][j16][2], byx = tb[w][j16][3];
  const float bzn = tb[w][j16][4], bzx = tb[w][j16][5];

  unsigned wkh = __float_as_uint(1e10f), wkl = 0;  // cached wave key
  int cur = 0;
  float lx = X[0], ly = X[1], lz = X[2];

  for (int k = 0; k < NP; ++k) {
    if (t == 0) fps_idx[b * NP + k] = cur;

    // lane j16 tests tile (j16, w) against ITS OWN cached max (exact skip)
    const float th = __uint_as_float((unsigned)(tkL[w][j16] >> 32));
    const float ddx = fmaxf(fmaxf(bxn - lx, lx - bxx), 0.0f);
    const float ddy = fmaxf(fmaxf(byn - ly, ly - byx), 0.0f);
    const float ddz = fmaxf(fmaxf(bzn - lz, lz - bzx), 0.0f);
    const float db2 = ((ddx * ddx) + (ddy * ddy)) + (ddz * ddz);
    const bool act = db2 <= th * 1.00001f;
    const unsigned msk = __builtin_amdgcn_readfirstlane(
        (unsigned)__ballot(act) & 0xFFFFu);

    if (msk) {
      // per active tile: 10-op update + fused exact key recompute (RED6 u64);
      // chains across tiles are independent -> pipeline-overlapped
#define UPD(J) if (msk & (1u << (J))) {                                  \
        const float2 v = XY[((J) << 10) + t];                            \
        const float dx = v.x - lx, dy = v.y - ly, dz = z[(J)] - lz;      \
        const float d = ((dx * dx) + (dy * dy)) + (dz * dz);             \
        const float nd = fminf(dist[(J)], d);                            \
        dist[(J)] = nd;                                                  \
        unsigned kh = __float_as_uint(nd), kl = pl[(J)];                 \
        RED64(kh, kl)                                                    \
        if (lane == 63) tkL[w][(J)] = ((unsigned long long)kh << 32) | kl; }
      UPD(0)  UPD(1)  UPD(2)  UPD(3)  UPD(4)  UPD(5)  UPD(6)  UPD(7)
      UPD(8)  UPD(9)  UPD(10) UPD(11) UPD(12) UPD(13) UPD(14) UPD(15)
#undef UPD
      // wave key = dpp4 over the 16 cached tile keys
      const unsigned long long tkj = tkL[w][j16];
      unsigned h = (unsigned)(tkj >> 32), l2 = (unsigned)tkj;
      dpp_max64<0x111>(h, l2);
      dpp_max64<0x112>(h, l2);
      dpp_max64<0x114>(h, l2);
      dpp_max64<0x118>(h, l2);
      wkh = (unsigned)__builtin_amdgcn_readlane((int)h, 15);
      wkl = (unsigned)__builtin_amdgcn_readlane((int)l2, 15);
    }
    const int p = k & 1;
    if (lane == 0)
      redk[p][w] = ((unsigned long long)wkh << 32) | wkl;
    __syncthreads();

    // cross-wave combine; speculative winner-z load overlaps the DPP chain
    const unsigned long long kj = redk[p][j16];
    const unsigned shi = (unsigned)(kj >> 32), slo = (unsigned)kj;
    const float sgz = ZS[(int)(slo & 0x3FFFu)];  // global (L2), overlapped
    unsigned h2 = shi, l3 = slo;
    dpp_max64<0x111>(h2, l3);
    dpp_max64<0x112>(h2, l3);
    dpp_max64<0x114>(h2, l3);
    dpp_max64<0x118>(h2, l3);                   // lane 15 of each row = global max
    const unsigned kmh = (unsigned)__builtin_amdgcn_readlane((int)h2, 15);
    const unsigned kml = (unsigned)__builtin_amdgcn_readlane((int)l3, 15);
    cur = (int)((kml >> 14) & 0x3FFFu) ^ 0x3FFF;
    const unsigned long long tmsk = __ballot(shi == kmh && slo == kml);
    const int bwl = (int)__builtin_ctzll(tmsk);
    lz = __uint_as_float((unsigned)__builtin_amdgcn_readlane(__float_as_int(sgz), bwl));
    const float2 sxy = XY[(int)(kml & 0x3FFFu)];  // uniform LDS broadcast read
    lx = sxy.x; ly = sxy.y;
    // one barrier/iter: parity double-buffer makes overwrite-while-read impossible
  }
}

// ---------------- Ball query ----------------
__global__ __launch_bounds__(256)
void ballq_kernel(const float* __restrict__ xyz, const int* __restrict__ fps_idx,
                  int* __restrict__ ball_idx)
{
#pragma clang fp contract(off)
  const int gw = (int)((blockIdx.x * blockDim.x + threadIdx.x) >> 6);
  const int lane = threadIdx.x & 63;
  const int b = gw >> 10, s = gw & 1023;
  const float* __restrict__ X = xyz + (size_t)b * NPTS * 3;
  const int ci = fps_idx[b * NP + s];
  const float cx = X[ci * 3 + 0], cy = X[ci * 3 + 1], cz = X[ci * 3 + 2];
  const float n2 = ((cx * cx) + (cy * cy)) + (cz * cz);
  int* __restrict__ out = ball_idx + (size_t)(b * NP + s) * NS;

  int cnt = 0;
  int first = -1;
  for (int c0 = 0; c0 < NPTS && cnt < NS; c0 += 64) {
    const int p = c0 + lane;
    const float x = X[p * 3 + 0], y = X[p * 3 + 1], z = X[p * 3 + 2];
    const float x2 = ((x * x) + (y * y)) + (z * z);
    const float dt = ((cx * x) + (cy * y)) + (cz * z);
    const float d2 = (n2 + x2) - (2.0f * dt);
    const bool inball = d2 < 0.04f;
    const unsigned long long mm = __ballot(inball);
    if (inball) {
      const int pos = cnt + __popcll(mm & ((1ull << lane) - 1ull));
      if (pos < NS) out[pos] = p;
    }
    if (first < 0 && mm != 0ull) first = c0 + __builtin_ctzll(mm);
    cnt += __popcll(mm);
  }
  if (cnt < NS) {
    if (first < 0) first = 0;
    if (lane >= cnt && lane < NS) out[lane] = first;
  }
}

// ---------------- Transpose feats [B][C][N] -> [B][N][C] ----------------
__global__ __launch_bounds__(256)
void transpose_kernel(const float* __restrict__ feats, float* __restrict__ featsT)
{
  __shared__ float t[32][33];
  const int b = blockIdx.z;
  const int cb = blockIdx.y * 32;
  const int nb = blockIdx.x * 32;
  const int tx = threadIdx.x;
  const int ty = threadIdx.y;
  const float* __restrict__ F = feats + (size_t)b * CIN * NPTS;
#pragma unroll
  for (int i = 0; i < 32; i += 8)
    t[ty + i][tx] = F[(size_t)(cb + ty + i) * NPTS + nb + tx];
  __syncthreads();
  float* __restrict__ FT_ = featsT + (size_t)b * NPTS * CIN;
#pragma unroll
  for (int i = 0; i < 32; i += 8)
    FT_[(size_t)(nb + ty + i) * CIN + cb + tx] = t[tx][ty + i];
}

// ---------------- Gather + max-pool ----------------
__global__ __launch_bounds__(128)
void pool_kernel(const float* __restrict__ featsT, const int* __restrict__ ball_idx,
                 float* __restrict__ pooled)
{
  const int bs = blockIdx.x;
  const int c = threadIdx.x;
  const int b = bs >> 10;
  const int* __restrict__ idx = ball_idx + (size_t)bs * NS;
  const float* __restrict__ FT_ = featsT + (size_t)b * NPTS * CIN;
  float m = -INFINITY;
#pragma unroll 4
  for (int k = 0; k < NS; ++k) {
    const int n = idx[k];
    m = fmaxf(m, FT_[(size_t)n * CIN + c]);
  }
  pooled[(size_t)bs * CIN + c] = m;
}

// ---------------- 1x1 conv + BN + LeakyReLU ----------------
#define GO 128
#define GS 64
__global__ __launch_bounds__(256, 1)
void gemm_kernel(const float* __restrict__ pooled, const float* __restrict__ W,
                 const float* __restrict__ gamma, const float* __restrict__ beta,
                 const float* __restrict__ mean, const float* __restrict__ var,
                 float* __restrict__ out)
{
  __shared__ float Wt[128 * 132];
  __shared__ float Pl[128 * 68];
  const int b = blockIdx.z;
  const int ob = blockIdx.y * GO;
  const int sb = blockIdx.x * GS;
  const int tid = threadIdx.x;

  for (int i = tid; i < GO * 128; i += 256) {
    const int o = i >> 7, c = i & 127;
    Wt[c * 132 + o] = W[(ob + o) * 128 + c];
  }
  const float* __restrict__ P = pooled + (size_t)(b * NP + sb) * 128;
  for (int i = tid; i < GS * 128; i += 256) {
    const int s = i >> 7, c = i & 127;
    Pl[c * 68 + s] = P[s * 128 + c];
  }
  __syncthreads();

  const int to = tid & 31, ts = tid >> 5;
  const int o0 = to * 4, s0 = ts * 8;
  float acc[4][8];
#pragma unroll
  for (int o = 0; o < 4; ++o)
#pragma unroll
    for (int j = 0; j < 8; ++j) acc[o][j] = 0.0f;

  for (int c = 0; c < 128; ++c) {
    const float4 wv = *(const float4*)&Wt[c * 132 + o0];
    const float4 pa = *(const float4*)&Pl[c * 68 + s0];
    const float4 pb = *(const float4*)&Pl[c * 68 + s0 + 4];
    const float wr[4] = {wv.x, wv.y, wv.z, wv.w};
    const float pr[8] = {pa.x, pa.y, pa.z, pa.w, pb.x, pb.y, pb.z, pb.w};
#pragma unroll
    for (int o = 0; o < 4; ++o)
#pragma unroll
      for (int j = 0; j < 8; ++j)
        acc[o][j] = fmaf(wr[o], pr[j], acc[o][j]);
  }

#pragma unroll
  for (int o = 0; o < 4; ++o) {
    const int oo = ob + o0 + o;
    const float sc = gamma[oo] / sqrtf(var[oo] + 1e-5f);
    const float sh = beta[oo] - mean[oo] * sc;
    float r[8];
#pragma unroll
    for (int j = 0; j < 8; ++j) {
      const float y = fmaf(acc[o][j], sc, sh);
      r[j] = (y >= 0.0f) ? y : 0.2f * y;
    }
    float* __restrict__ O = out + (size_t)(b * COUT + oo) * NP + sb + s0;
    *(float4*)&O[0] = make_float4(r[0], r[1], r[2], r[3]);
    *(float4*)&O[4] = make_float4(r[4], r[5], r[6], r[7]);
  }
}

// ---------------- launch ----------------
extern "C" void kernel_launch(void* const* d_in, const int* in_sizes, int n_in,
                              void* d_out, int out_size, void* d_ws, size_t ws_size,
                              hipStream_t stream)
{
  (void)in_sizes; (void)n_in; (void)out_size; (void)ws_size;
  const float* xyz   = (const float*)d_in[0];
  const float* feats = (const float*)d_in[1];
  const float* W     = (const float*)d_in[2];
  const float* gamma = (const float*)d_in[3];
  const float* beta  = (const float*)d_in[4];
  const float* mean  = (const float*)d_in[5];
  const float* var   = (const float*)d_in[6];
  float* out = (float*)d_out;

  char* ws = (char*)d_ws;
  // fps_idx [32KB] @0 | ball_idx [1MB] @32768 | featsT [64MB] @1081344 |
  // pooled [4MB] @68190208. Sort scratch aliases featsT head (dead before
  // transpose runs; stream order guarantees no overlap-in-time).
  int*   fps_idx  = (int*)(ws + 0);
  int*   ball_idx = (int*)(ws + 32768);
  char*  fbase    = ws + 1081344;
  float* featsT   = (float*)fbase;
  float* pooled   = (float*)(ws + 68190208);

  float2* sxy2S  = (float2*)(fbase + 0);        // 1 MB
  float*  szS    = (float*)(fbase + 1048576);   // 512 KB
  int*    siS    = (int*)(fbase + 1572864);     // 512 KB
  int*    hist   = (int*)(fbase + 2097152);     // 16 KB
  int*    cursor = (int*)(fbase + 2113536);     // 16 KB

  zero_hist_kernel<<<NBATCH, NCELL, 0, stream>>>(hist);
  hist_kernel<<<(NBATCH * NPTS) / 256, 256, 0, stream>>>(xyz, hist);
  scan_kernel<<<NBATCH, NCELL, 0, stream>>>(hist, cursor);
  scatter_kernel<<<(NBATCH * NPTS) / 256, 256, 0, stream>>>(xyz, cursor, sxy2S, szS, siS);
  fps_kernel<<<NBATCH, FPS_T, 0, stream>>>(xyz, sxy2S, szS, siS, fps_idx);
  ballq_kernel<<<(NBATCH * NP) / 4, 256, 0, stream>>>(xyz, fps_idx, ball_idx);
  transpose_kernel<<<dim3(NPTS / 32, CIN / 32, NBATCH), dim3(32, 8), 0, stream>>>(feats, featsT);
  pool_kernel<<<NBATCH * NP, CIN, 0, stream>>>(featsT, ball_idx, pooled);
  gemm_kernel<<<dim3(NP / GS, COUT / GO, NBATCH), 256, 0, stream>>>(pooled, W, gamma, beta, mean, var, out);
}